// Round 2
// baseline (1344.230 us; speedup 1.0000x reference)
//
#include <hip/hip_runtime.h>

#define N_ATOMS   100000
#define N_BONDS   200000
#define MAX_NB    6
#define AF        39
#define BFEAT     50      // 39 + 11
#define H         128
#define DEPTH     6

typedef unsigned short ushort_t;
typedef unsigned int   uint_t;

__device__ inline float bf2f(ushort_t u) {
    union { uint_t i; float f; } v; v.i = ((uint_t)u) << 16; return v.f;
}
__device__ inline ushort_t f2bf(float f) {
    union { float f; uint_t i; } v; v.f = f;
    uint_t x = v.i;
    uint_t r = (x + 0x7fffu + ((x >> 16) & 1u)) >> 16;   // RNE
    return (ushort_t)r;
}

// ---------------------------------------------------------------------------
// Kernel 1: binput = fbonds @ W_i^T (bf16 out); msg = relu(binput) (bf16 out)
// 32 bonds/block, 256 threads. LDS ~34 KB.
// ---------------------------------------------------------------------------
#define BPB_I 32
__global__ __launch_bounds__(256) void k_binput(const float* __restrict__ fbonds,
                                                const float* __restrict__ W_i,
                                                ushort_t* __restrict__ binput,
                                                ushort_t* __restrict__ msg) {
    __shared__ float sW[H][54];        // stride 54 words: (22h)%32 -> <=4-way
    __shared__ float sF[BPB_I][52];    // stride 52 words, 8B-aligned float2
    const int t = threadIdx.x;
    for (int i = t; i < H * BFEAT; i += 256)
        sW[i / BFEAT][i % BFEAT] = W_i[i];
    const int b0 = blockIdx.x * BPB_I;
    for (int i = t; i < BPB_I * BFEAT; i += 256)
        sF[i / BFEAT][i % BFEAT] = fbonds[b0 * BFEAT + i];
    __syncthreads();

    const int h = t & (H - 1);
    const int g = t >> 7;              // 0..1
    const int i0 = g * (BPB_I / 2);
    float acc[BPB_I / 2];
#pragma unroll
    for (int ii = 0; ii < BPB_I / 2; ++ii) acc[ii] = 0.f;
    for (int f = 0; f < BFEAT; f += 2) {
        const float2 w = *(const float2*)&sW[h][f];
#pragma unroll
        for (int ii = 0; ii < BPB_I / 2; ++ii) {
            const float2 x = *(const float2*)&sF[i0 + ii][f];
            acc[ii] += w.x * x.x + w.y * x.y;
        }
    }
#pragma unroll
    for (int ii = 0; ii < BPB_I / 2; ++ii) {
        const int b = b0 + i0 + ii;
        binput[b * H + h] = f2bf(acc[ii]);
        msg[b * H + h]    = f2bf(acc[ii] > 0.f ? acc[ii] : 0.f);
    }
}

// ---------------------------------------------------------------------------
// Kernel 2: one message-passing step (bf16 msg storage, fp32 accumulation).
//   nei[b] = sum_j msg_in[bgraph[b][j]]
//   msg_out[b] = relu(binput[b] + W_h @ nei[b])
// 16 bonds/block, 256 threads. LDS ~42 KB.
// ---------------------------------------------------------------------------
#define BPB_M 16
__global__ __launch_bounds__(256) void k_mp(const ushort_t* __restrict__ msg_in,
                                            const int* __restrict__ bgraph,
                                            const float* __restrict__ W_h,
                                            const ushort_t* __restrict__ binput,
                                            ushort_t* __restrict__ msg_out) {
    __shared__ ushort_t sW[H][132];    // bf16, 264B row stride (8B aligned)
    __shared__ float    sN[BPB_M][H];  // 512B row stride, float4-friendly
    __shared__ int      sIdx[BPB_M][MAX_NB];
    const int t = threadIdx.x;
    for (int i = t; i < H * H; i += 256)
        sW[i >> 7][i & (H - 1)] = f2bf(W_h[i]);
    const int b0 = blockIdx.x * BPB_M;
    if (t < BPB_M * MAX_NB)
        sIdx[t / MAX_NB][t % MAX_NB] = bgraph[b0 * MAX_NB + t];
    __syncthreads();

    // phase 1: gather-sum. Each thread owns 2 columns for 4 bonds.
    const int c   = t & 63;
    const int grp = t >> 6;            // 0..3
    for (int s = 0; s < BPB_M / 4; ++s) {
        const int i = grp * (BPB_M / 4) + s;
        float a0 = 0.f, a1 = 0.f;
#pragma unroll
        for (int j = 0; j < MAX_NB; ++j) {
            const int idx = sIdx[i][j];
            const uint_t v = *(const uint_t*)(msg_in + (size_t)idx * H + 2 * c);
            a0 += bf2f((ushort_t)(v & 0xffffu));
            a1 += bf2f((ushort_t)(v >> 16));
        }
        sN[i][2 * c]     = a0;
        sN[i][2 * c + 1] = a1;
    }
    __syncthreads();

    // phase 2: matvec, 8 bonds register-blocked per thread
    const int h = t & (H - 1);
    const int g = t >> 7;
    const int i0 = g * (BPB_M / 2);
    float acc[BPB_M / 2];
#pragma unroll
    for (int ii = 0; ii < BPB_M / 2; ++ii) acc[ii] = 0.f;
    for (int kk = 0; kk < H; kk += 4) {
        const uint2 wp = *(const uint2*)&sW[h][kk];
        const float w0 = bf2f((ushort_t)(wp.x & 0xffffu));
        const float w1 = bf2f((ushort_t)(wp.x >> 16));
        const float w2 = bf2f((ushort_t)(wp.y & 0xffffu));
        const float w3 = bf2f((ushort_t)(wp.y >> 16));
#pragma unroll
        for (int ii = 0; ii < BPB_M / 2; ++ii) {
            const float4 n = *(const float4*)&sN[i0 + ii][kk];
            acc[ii] += w0 * n.x + w1 * n.y + w2 * n.z + w3 * n.w;
        }
    }
#pragma unroll
    for (int ii = 0; ii < BPB_M / 2; ++ii) {
        const int b = b0 + i0 + ii;
        const float v = bf2f(binput[(size_t)b * H + h]) + acc[ii];
        msg_out[(size_t)b * H + h] = f2bf(v > 0.f ? v : 0.f);
    }
}

// ---------------------------------------------------------------------------
// Kernel 3: atom aggregation + output layer (fp32 out).
//   a_nei[a] = sum_j msg[agraph[a][j]]
//   out[a] = relu(b_o + W_o @ concat(fatoms[a], a_nei[a]))
// 16 atoms/block, 256 threads. LDS ~55 KB.
// ---------------------------------------------------------------------------
#define APB 16
#define OF  (AF + H)   // 167
__global__ __launch_bounds__(256) void k_out(const float* __restrict__ fatoms,
                                             const ushort_t* __restrict__ msg,
                                             const int* __restrict__ agraph,
                                             const float* __restrict__ W_o,
                                             const float* __restrict__ b_o,
                                             float* __restrict__ out) {
    __shared__ ushort_t sW[H][170];    // bf16, 340B row stride
    __shared__ float    sIn[APB][168]; // 672B row stride (8B aligned)
    __shared__ int      sIdx[APB][MAX_NB];
    const int t = threadIdx.x;
    for (int i = t; i < H * OF; i += 256)
        sW[i / OF][i % OF] = f2bf(W_o[i]);
    const int a0 = blockIdx.x * APB;
    if (t < APB * MAX_NB)
        sIdx[t / MAX_NB][t % MAX_NB] = agraph[a0 * MAX_NB + t];
    for (int i = t; i < APB * AF; i += 256)
        sIn[i / AF][i % AF] = fatoms[a0 * AF + i];
    __syncthreads();

    // a_nei gather: each thread owns 2 columns for 4 atoms.
    const int c   = t & 63;
    const int grp = t >> 6;
    for (int s = 0; s < APB / 4; ++s) {
        const int i = grp * (APB / 4) + s;
        float a0v = 0.f, a1v = 0.f;
#pragma unroll
        for (int j = 0; j < MAX_NB; ++j) {
            const int idx = sIdx[i][j];
            const uint_t v = *(const uint_t*)(msg + (size_t)idx * H + 2 * c);
            a0v += bf2f((ushort_t)(v & 0xffffu));
            a1v += bf2f((ushort_t)(v >> 16));
        }
        sIn[i][AF + 2 * c]     = a0v;
        sIn[i][AF + 2 * c + 1] = a1v;
    }
    __syncthreads();

    const int h = t & (H - 1);
    const int g = t >> 7;
    const int i0 = g * (APB / 2);
    float acc[APB / 2];
#pragma unroll
    for (int ii = 0; ii < APB / 2; ++ii) acc[ii] = 0.f;
    for (int f = 0; f < OF - 1; f += 2) {
        const uint_t wp = *(const uint_t*)&sW[h][f];
        const float w0 = bf2f((ushort_t)(wp & 0xffffu));
        const float w1 = bf2f((ushort_t)(wp >> 16));
#pragma unroll
        for (int ii = 0; ii < APB / 2; ++ii) {
            const float2 x = *(const float2*)&sIn[i0 + ii][f];
            acc[ii] += w0 * x.x + w1 * x.y;
        }
    }
    {   // tail f = 166
        const float w0 = bf2f(sW[h][OF - 1]);
#pragma unroll
        for (int ii = 0; ii < APB / 2; ++ii)
            acc[ii] += w0 * sIn[i0 + ii][OF - 1];
    }
    const float bias = b_o[h];
#pragma unroll
    for (int ii = 0; ii < APB / 2; ++ii) {
        const int a = a0 + i0 + ii;
        const float v = bias + acc[ii];
        out[(size_t)a * H + h] = v > 0.f ? v : 0.f;
    }
}

// ---------------------------------------------------------------------------
extern "C" void kernel_launch(void* const* d_in, const int* in_sizes, int n_in,
                              void* d_out, int out_size, void* d_ws, size_t ws_size,
                              hipStream_t stream) {
    const float* fatoms = (const float*)d_in[0];
    const float* fbonds = (const float*)d_in[1];
    const int*   agraph = (const int*)d_in[2];
    const int*   bgraph = (const int*)d_in[3];
    const float* W_i    = (const float*)d_in[4];
    const float* W_h    = (const float*)d_in[5];
    const float* W_o    = (const float*)d_in[6];
    const float* b_o    = (const float*)d_in[7];
    float* out = (float*)d_out;

    const size_t MSG_BYTES = (size_t)N_BONDS * H * sizeof(ushort_t);   // 51.2 MB
    char* ws = (char*)d_ws;
    ushort_t* binput = (ushort_t*)(ws);
    ushort_t* msgA   = (ushort_t*)(ws + MSG_BYTES);
    ushort_t* msgB   = (ushort_t*)(ws + 2 * MSG_BYTES);

    k_binput<<<N_BONDS / BPB_I, 256, 0, stream>>>(fbonds, W_i, binput, msgA);

    ushort_t* cur = msgA;
    ushort_t* nxt = msgB;
    for (int d = 0; d < DEPTH - 1; ++d) {
        k_mp<<<N_BONDS / BPB_M, 256, 0, stream>>>(cur, bgraph, W_h, binput, nxt);
        ushort_t* tmp = cur; cur = nxt; nxt = tmp;
    }

    k_out<<<N_ATOMS / APB, 256, 0, stream>>>(fatoms, cur, agraph, W_o, b_o, out);
}

// Round 3
// 722.575 us; speedup vs baseline: 1.8603x; 1.8603x over previous
//
#include <hip/hip_runtime.h>

#define N_ATOMS   100000
#define N_BONDS   200000
#define MAX_NB    6
#define AF        39
#define BFEAT     50      // 39 + 11
#define H         128
#define DEPTH     6

typedef unsigned short ushort_t;
typedef unsigned int   uint_t;

typedef __attribute__((ext_vector_type(8))) short  bf16x8;
typedef __attribute__((ext_vector_type(4))) float  f32x4;

__device__ inline float bf2f(ushort_t u) {
    union { uint_t i; float f; } v; v.i = ((uint_t)u) << 16; return v.f;
}
__device__ inline ushort_t f2bf(float f) {
    union { float f; uint_t i; } v; v.f = f;
    uint_t x = v.i;
    uint_t r = (x + 0x7fffu + ((x >> 16) & 1u)) >> 16;   // RNE
    return (ushort_t)r;
}
__device__ inline uint_t pack2(float a, float b) {
    return (uint_t)f2bf(a) | ((uint_t)f2bf(b) << 16);
}
// relu on a packed pair of bf16 (sign bit -> 0)
__device__ inline uint_t relu2(uint_t w) {
    uint_t lo = w & 0xffffu, hi = w >> 16;
    if (lo & 0x8000u) lo = 0;
    if (hi & 0x8000u) hi = 0;
    return lo | (hi << 16);
}

// ---------------------------------------------------------------------------
// Kernel 1 (MFMA): binput = fbonds @ W_i^T (bf16); msg = relu(binput) (bf16)
// 64 bonds/block, 256 threads (4 waves). K padded 50 -> 64 (2 k-steps).
// LDS ~36 KB -> 4 blocks/CU.
// ---------------------------------------------------------------------------
__global__ __launch_bounds__(256) void k_binput(const float* __restrict__ fbonds,
                                                const float* __restrict__ W_i,
                                                ushort_t* __restrict__ binput,
                                                ushort_t* __restrict__ msg) {
    __shared__ __align__(16) ushort_t sB[H][72];    // W_i bf16 [n][k], stride 72 (bank 4n%32 -> 2-way free)
    __shared__ __align__(16) ushort_t sA[64][136];  // A bf16 [m][k]; reused as bf16 C-stage
    const int t = threadIdx.x;
    const int b0 = blockIdx.x * 64;

    for (int i = t; i < H * 64; i += 256) {
        const int n = i >> 6, k = i & 63;
        sB[n][k] = (k < BFEAT) ? f2bf(W_i[n * BFEAT + k]) : (ushort_t)0;
    }
    for (int i = t; i < 64 * BFEAT; i += 256) {
        const int m = i / BFEAT, k = i % BFEAT;
        sA[m][k] = f2bf(fbonds[(size_t)b0 * BFEAT + i]);
    }
    for (int i = t; i < 64 * (64 - BFEAT); i += 256) {
        const int m = i / (64 - BFEAT), k = i % (64 - BFEAT);
        sA[m][BFEAT + k] = 0;
    }
    __syncthreads();

    const int w    = t >> 6;         // wave 0..3 -> m-tile
    const int lane = t & 63;
    const int col  = lane & 15;
    const int kg   = lane >> 4;      // 0..3
    const int m    = 16 * w + col;

    f32x4 acc[8];
#pragma unroll
    for (int nt = 0; nt < 8; ++nt) acc[nt] = (f32x4){0.f, 0.f, 0.f, 0.f};

#pragma unroll
    for (int ks = 0; ks < 2; ++ks) {
        const int k = ks * 32 + kg * 8;
        const bf16x8 a = *(const bf16x8*)&sA[m][k];
#pragma unroll
        for (int nt = 0; nt < 8; ++nt) {
            const bf16x8 b = *(const bf16x8*)&sB[nt * 16 + col][k];
            acc[nt] = __builtin_amdgcn_mfma_f32_16x16x32_bf16(a, b, acc[nt], 0, 0, 0);
        }
    }
    __syncthreads();   // done reading sA; reuse as C-stage

    const int row0 = kg * 4;
#pragma unroll
    for (int nt = 0; nt < 8; ++nt)
#pragma unroll
        for (int r = 0; r < 4; ++r)
            sA[16 * w + row0 + r][nt * 16 + col] = f2bf(acc[nt][r]);
    __syncthreads();

    for (int i = t; i < 64 * 16; i += 256) {
        const int row = i >> 4, c0 = (i & 15) * 8;
        const uint4 v = *(const uint4*)&sA[row][c0];
        uint4 rl;
        rl.x = relu2(v.x); rl.y = relu2(v.y); rl.z = relu2(v.z); rl.w = relu2(v.w);
        const size_t off = ((size_t)(b0 + row) * H + c0);
        *(uint4*)(binput + off) = v;
        *(uint4*)(msg + off)    = rl;
    }
}

// ---------------------------------------------------------------------------
// Kernel 2 (MFMA): one message-passing step.
//   nei[b] = sum_j msg_in[bgraph[b][j]]   (bf16 rows, fp32 sum, bf16 A-frag)
//   msg_out[b] = relu(binput[b] + nei[b] @ W_h^T)
// 64 bonds/block, 256 threads. LDS ~70 KB -> 2 blocks/CU.
// ---------------------------------------------------------------------------
__global__ __launch_bounds__(256) void k_mp(const ushort_t* __restrict__ msg_in,
                                            const int* __restrict__ bgraph,
                                            const float* __restrict__ W_h,
                                            const ushort_t* __restrict__ binput,
                                            ushort_t* __restrict__ msg_out) {
    __shared__ __align__(16) ushort_t sB[H][136];   // W_h bf16 [n][k], 34816 B
    __shared__ __align__(16) float    sC[64][132];  // f32 C-stage, 33792 B; aliased as A bf16 [64][136]
    __shared__ int sIdx[64][MAX_NB];
    ushort_t (*sA)[136] = (ushort_t(*)[136])&sC[0][0];
    const int t = threadIdx.x;
    const int b0 = blockIdx.x * 64;

    {   // stage W_h as bf16 rows (B[n][k] = W_h[n][k]) — float4 loads, b64 LDS writes
        const float4* W4 = (const float4*)W_h;
        for (int i = t; i < (H * H) / 4; i += 256) {
            const float4 v = W4[i];
            const int n = i >> 5, k0 = (i & 31) * 4;
            uint2 u; u.x = pack2(v.x, v.y); u.y = pack2(v.z, v.w);
            *(uint2*)&sB[n][k0] = u;
        }
    }
    for (int i = t; i < 64 * MAX_NB; i += 256)
        sIdx[i / MAX_NB][i % MAX_NB] = bgraph[(size_t)b0 * MAX_NB + i];
    __syncthreads();

    // gather-sum -> bf16 A-fragments. 4 passes; thread = (bond-in-pass, col-group)
    {
        const int bi = t >> 4;          // 0..15
        const int c0 = (t & 15) * 8;    // col base
#pragma unroll
        for (int p = 0; p < 4; ++p) {
            const int i = p * 16 + bi;
            float a[8];
#pragma unroll
            for (int q = 0; q < 8; ++q) a[q] = 0.f;
#pragma unroll
            for (int j = 0; j < MAX_NB; ++j) {
                const int idx = sIdx[i][j];
                const uint4 v = *(const uint4*)(msg_in + (size_t)idx * H + c0);
                a[0] += bf2f((ushort_t)(v.x & 0xffffu)); a[1] += bf2f((ushort_t)(v.x >> 16));
                a[2] += bf2f((ushort_t)(v.y & 0xffffu)); a[3] += bf2f((ushort_t)(v.y >> 16));
                a[4] += bf2f((ushort_t)(v.z & 0xffffu)); a[5] += bf2f((ushort_t)(v.z >> 16));
                a[6] += bf2f((ushort_t)(v.w & 0xffffu)); a[7] += bf2f((ushort_t)(v.w >> 16));
            }
            uint4 u;
            u.x = pack2(a[0], a[1]); u.y = pack2(a[2], a[3]);
            u.z = pack2(a[4], a[5]); u.w = pack2(a[6], a[7]);
            *(uint4*)&sA[i][c0] = u;
        }
    }
    __syncthreads();

    const int w    = t >> 6;
    const int lane = t & 63;
    const int col  = lane & 15;
    const int kg   = lane >> 4;
    const int m    = 16 * w + col;

    f32x4 acc[8];
#pragma unroll
    for (int nt = 0; nt < 8; ++nt) acc[nt] = (f32x4){0.f, 0.f, 0.f, 0.f};

#pragma unroll
    for (int ks = 0; ks < 4; ++ks) {
        const int k = ks * 32 + kg * 8;
        const bf16x8 a = *(const bf16x8*)&sA[m][k];
#pragma unroll
        for (int nt = 0; nt < 8; ++nt) {
            const bf16x8 b = *(const bf16x8*)&sB[nt * 16 + col][k];
            acc[nt] = __builtin_amdgcn_mfma_f32_16x16x32_bf16(a, b, acc[nt], 0, 0, 0);
        }
    }
    __syncthreads();   // done reading sA; sC overlays it

    const int row0 = kg * 4;
#pragma unroll
    for (int nt = 0; nt < 8; ++nt)
#pragma unroll
        for (int r = 0; r < 4; ++r)
            sC[16 * w + row0 + r][nt * 16 + col] = acc[nt][r];
    __syncthreads();

    // coalesced epilogue: +binput, relu, pack bf16
    for (int i = t; i < 64 * 16; i += 256) {
        const int row = i >> 4, c0 = (i & 15) * 8;
        const size_t off = (size_t)(b0 + row) * H + c0;
        const uint4 bi4 = *(const uint4*)(binput + off);
        const float* cp = &sC[row][c0];
        uint4 o;
        float v0, v1;
        v0 = bf2f((ushort_t)(bi4.x & 0xffffu)) + cp[0]; v1 = bf2f((ushort_t)(bi4.x >> 16)) + cp[1];
        o.x = pack2(v0 > 0.f ? v0 : 0.f, v1 > 0.f ? v1 : 0.f);
        v0 = bf2f((ushort_t)(bi4.y & 0xffffu)) + cp[2]; v1 = bf2f((ushort_t)(bi4.y >> 16)) + cp[3];
        o.y = pack2(v0 > 0.f ? v0 : 0.f, v1 > 0.f ? v1 : 0.f);
        v0 = bf2f((ushort_t)(bi4.z & 0xffffu)) + cp[4]; v1 = bf2f((ushort_t)(bi4.z >> 16)) + cp[5];
        o.z = pack2(v0 > 0.f ? v0 : 0.f, v1 > 0.f ? v1 : 0.f);
        v0 = bf2f((ushort_t)(bi4.w & 0xffffu)) + cp[6]; v1 = bf2f((ushort_t)(bi4.w >> 16)) + cp[7];
        o.w = pack2(v0 > 0.f ? v0 : 0.f, v1 > 0.f ? v1 : 0.f);
        *(uint4*)(msg_out + off) = o;
    }
}

// ---------------------------------------------------------------------------
// Kernel 3 (MFMA): atom aggregation + output layer (fp32 out).
//   A = [a_nei(128) | fatoms(39) | pad(25)]  -> K = 192 (6 k-steps)
//   B[n][k]: k<128 -> W_o[n][39+k]; 128<=k<167 -> W_o[n][k-128]; else 0
// 64 atoms/block, 256 threads. LDS ~78 KB -> 2 blocks/CU.
// ---------------------------------------------------------------------------
#define KO 192
__global__ __launch_bounds__(256) void k_out(const float* __restrict__ fatoms,
                                             const ushort_t* __restrict__ msg,
                                             const int* __restrict__ agraph,
                                             const float* __restrict__ W_o,
                                             const float* __restrict__ b_o,
                                             float* __restrict__ out) {
    __shared__ __align__(16) ushort_t sB[H][200];   // 51200 B, stride 100 words -> 2-way free
    __shared__ __align__(16) ushort_t sA[64][200];  // 25600 B
    __shared__ int sIdx[64][MAX_NB];
    const int t = threadIdx.x;
    const int a0 = blockIdx.x * 64;

    for (int i = t; i < H * KO; i += 256) {
        const int n = i / KO, k = i % KO;
        float v = 0.f;
        if (k < H)            v = W_o[(size_t)n * (AF + H) + AF + k];
        else if (k < H + AF)  v = W_o[(size_t)n * (AF + H) + (k - H)];
        sB[n][k] = f2bf(v);
    }
    for (int i = t; i < 64 * MAX_NB; i += 256) {
        const int a = a0 + i / MAX_NB;
        sIdx[i / MAX_NB][i % MAX_NB] = (a < N_ATOMS) ? agraph[(size_t)a * MAX_NB + (i % MAX_NB)] : 0;
    }
    for (int i = t; i < 64 * AF; i += 256) {
        const int row = i / AF, c = i % AF;
        const int a = a0 + row;
        sA[row][H + c] = (a < N_ATOMS) ? f2bf(fatoms[(size_t)a * AF + c]) : (ushort_t)0;
    }
    for (int i = t; i < 64 * (KO - H - AF); i += 256) {
        const int row = i / (KO - H - AF), c = i % (KO - H - AF);
        sA[row][H + AF + c] = 0;
    }
    __syncthreads();

    {   // a_nei gather -> sA cols 0..127
        const int bi = t >> 4;
        const int c0 = (t & 15) * 8;
#pragma unroll
        for (int p = 0; p < 4; ++p) {
            const int i = p * 16 + bi;
            float a[8];
#pragma unroll
            for (int q = 0; q < 8; ++q) a[q] = 0.f;
#pragma unroll
            for (int j = 0; j < MAX_NB; ++j) {
                const int idx = sIdx[i][j];
                const uint4 v = *(const uint4*)(msg + (size_t)idx * H + c0);
                a[0] += bf2f((ushort_t)(v.x & 0xffffu)); a[1] += bf2f((ushort_t)(v.x >> 16));
                a[2] += bf2f((ushort_t)(v.y & 0xffffu)); a[3] += bf2f((ushort_t)(v.y >> 16));
                a[4] += bf2f((ushort_t)(v.z & 0xffffu)); a[5] += bf2f((ushort_t)(v.z >> 16));
                a[6] += bf2f((ushort_t)(v.w & 0xffffu)); a[7] += bf2f((ushort_t)(v.w >> 16));
            }
            uint4 u;
            u.x = pack2(a[0], a[1]); u.y = pack2(a[2], a[3]);
            u.z = pack2(a[4], a[5]); u.w = pack2(a[6], a[7]);
            *(uint4*)&sA[i][c0] = u;
        }
    }
    __syncthreads();

    const int w    = t >> 6;
    const int lane = t & 63;
    const int col  = lane & 15;
    const int kg   = lane >> 4;
    const int m    = 16 * w + col;

    f32x4 acc[8];
#pragma unroll
    for (int nt = 0; nt < 8; ++nt) acc[nt] = (f32x4){0.f, 0.f, 0.f, 0.f};

#pragma unroll
    for (int ks = 0; ks < 6; ++ks) {
        const int k = ks * 32 + kg * 8;
        const bf16x8 a = *(const bf16x8*)&sA[m][k];
#pragma unroll
        for (int nt = 0; nt < 8; ++nt) {
            const bf16x8 b = *(const bf16x8*)&sB[nt * 16 + col][k];
            acc[nt] = __builtin_amdgcn_mfma_f32_16x16x32_bf16(a, b, acc[nt], 0, 0, 0);
        }
    }

    const int row0 = kg * 4;
#pragma unroll
    for (int nt = 0; nt < 8; ++nt) {
        const int h = nt * 16 + col;
        const float bo = b_o[h];
#pragma unroll
        for (int r = 0; r < 4; ++r) {
            const int a = a0 + 16 * w + row0 + r;
            if (a < N_ATOMS) {
                const float v = acc[nt][r] + bo;
                out[(size_t)a * H + h] = v > 0.f ? v : 0.f;
            }
        }
    }
}

// ---------------------------------------------------------------------------
extern "C" void kernel_launch(void* const* d_in, const int* in_sizes, int n_in,
                              void* d_out, int out_size, void* d_ws, size_t ws_size,
                              hipStream_t stream) {
    const float* fatoms = (const float*)d_in[0];
    const float* fbonds = (const float*)d_in[1];
    const int*   agraph = (const int*)d_in[2];
    const int*   bgraph = (const int*)d_in[3];
    const float* W_i    = (const float*)d_in[4];
    const float* W_h    = (const float*)d_in[5];
    const float* W_o    = (const float*)d_in[6];
    const float* b_o    = (const float*)d_in[7];
    float* out = (float*)d_out;

    const size_t MSG_BYTES = (size_t)N_BONDS * H * sizeof(ushort_t);   // 51.2 MB
    char* ws = (char*)d_ws;
    ushort_t* binput = (ushort_t*)(ws);
    ushort_t* msgA   = (ushort_t*)(ws + MSG_BYTES);
    ushort_t* msgB   = (ushort_t*)(ws + 2 * MSG_BYTES);

    k_binput<<<N_BONDS / 64, 256, 0, stream>>>(fbonds, W_i, binput, msgA);

    ushort_t* cur = msgA;
    ushort_t* nxt = msgB;
    for (int d = 0; d < DEPTH - 1; ++d) {
        k_mp<<<N_BONDS / 64, 256, 0, stream>>>(cur, bgraph, W_h, binput, nxt);
        ushort_t* tmp = cur; cur = nxt; nxt = tmp;
    }

    k_out<<<(N_ATOMS + 63) / 64, 256, 0, stream>>>(fatoms, cur, agraph, W_o, b_o, out);
}

// Round 4
// 713.223 us; speedup vs baseline: 1.8847x; 1.0131x over previous
//
#include <hip/hip_runtime.h>

#define N_ATOMS   100000
#define N_BONDS   200000
#define MAX_NB    6
#define AF        39
#define BFEAT     50      // 39 + 11
#define H         128
#define DEPTH     6
#define KO        192     // k_out GEMM K: 128 (a_nei) + 39 (fatoms) + 25 pad

typedef unsigned short ushort_t;
typedef unsigned int   uint_t;

typedef __attribute__((ext_vector_type(8))) short  bf16x8;
typedef __attribute__((ext_vector_type(4))) float  f32x4;

__device__ inline float bf2f(ushort_t u) {
    union { uint_t i; float f; } v; v.i = ((uint_t)u) << 16; return v.f;
}
__device__ inline ushort_t f2bf(float f) {
    union { float f; uint_t i; } v; v.f = f;
    uint_t x = v.i;
    uint_t r = (x + 0x7fffu + ((x >> 16) & 1u)) >> 16;   // RNE
    return (ushort_t)r;
}
__device__ inline uint_t pack2(float a, float b) {
    return (uint_t)f2bf(a) | ((uint_t)f2bf(b) << 16);
}
__device__ inline uint_t relu2(uint_t w) {
    uint_t lo = w & 0xffffu, hi = w >> 16;
    if (lo & 0x8000u) lo = 0;
    if (hi & 0x8000u) hi = 0;
    return lo | (hi << 16);
}
__device__ inline void addv(float* a, uint4 v) {
    a[0] += bf2f((ushort_t)(v.x & 0xffffu)); a[1] += bf2f((ushort_t)(v.x >> 16));
    a[2] += bf2f((ushort_t)(v.y & 0xffffu)); a[3] += bf2f((ushort_t)(v.y >> 16));
    a[4] += bf2f((ushort_t)(v.z & 0xffffu)); a[5] += bf2f((ushort_t)(v.z >> 16));
    a[6] += bf2f((ushort_t)(v.w & 0xffffu)); a[7] += bf2f((ushort_t)(v.w >> 16));
}

// ---------------------------------------------------------------------------
// Kernel 1 (MFMA): binput = fbonds @ W_i^T (bf16); msg = relu(binput) (bf16)
// ---------------------------------------------------------------------------
__global__ __launch_bounds__(256) void k_binput(const float* __restrict__ fbonds,
                                                const float* __restrict__ W_i,
                                                ushort_t* __restrict__ binput,
                                                ushort_t* __restrict__ msg) {
    __shared__ __align__(16) ushort_t sB[H][72];
    __shared__ __align__(16) ushort_t sA[64][136];
    const int t = threadIdx.x;
    const int b0 = blockIdx.x * 64;

    for (int i = t; i < H * 64; i += 256) {
        const int n = i >> 6, k = i & 63;
        sB[n][k] = (k < BFEAT) ? f2bf(W_i[n * BFEAT + k]) : (ushort_t)0;
    }
    for (int i = t; i < 64 * BFEAT; i += 256) {
        const int m = i / BFEAT, k = i % BFEAT;
        sA[m][k] = f2bf(fbonds[(size_t)b0 * BFEAT + i]);
    }
    for (int i = t; i < 64 * (64 - BFEAT); i += 256) {
        const int m = i / (64 - BFEAT), k = i % (64 - BFEAT);
        sA[m][BFEAT + k] = 0;
    }
    __syncthreads();

    const int w    = t >> 6;
    const int lane = t & 63;
    const int col  = lane & 15;
    const int kg   = lane >> 4;
    const int m    = 16 * w + col;

    f32x4 acc[8];
#pragma unroll
    for (int nt = 0; nt < 8; ++nt) acc[nt] = (f32x4){0.f, 0.f, 0.f, 0.f};

#pragma unroll
    for (int ks = 0; ks < 2; ++ks) {
        const int k = ks * 32 + kg * 8;
        const bf16x8 a = *(const bf16x8*)&sA[m][k];
#pragma unroll
        for (int nt = 0; nt < 8; ++nt) {
            const bf16x8 b = *(const bf16x8*)&sB[nt * 16 + col][k];
            acc[nt] = __builtin_amdgcn_mfma_f32_16x16x32_bf16(a, b, acc[nt], 0, 0, 0);
        }
    }
    __syncthreads();

    const int row0 = kg * 4;
#pragma unroll
    for (int nt = 0; nt < 8; ++nt)
#pragma unroll
        for (int r = 0; r < 4; ++r)
            sA[16 * w + row0 + r][nt * 16 + col] = f2bf(acc[nt][r]);
    __syncthreads();

    for (int i = t; i < 64 * 16; i += 256) {
        const int row = i >> 4, c0 = (i & 15) * 8;
        const uint4 v = *(const uint4*)&sA[row][c0];
        uint4 rl;
        rl.x = relu2(v.x); rl.y = relu2(v.y); rl.z = relu2(v.z); rl.w = relu2(v.w);
        const size_t off = ((size_t)(b0 + row) * H + c0);
        *(uint4*)(binput + off) = v;
        *(uint4*)(msg + off)    = rl;
    }
}

// ---------------------------------------------------------------------------
// Gather (bonds): nei[row] = bf16( sum_j msg[idx[row][j]] ), [nrows][128].
// One (row, col-group-of-8) per thread: 6 independent uint4 loads, no LDS,
// low VGPR -> full occupancy. Latency-hiding by TLP.
// ---------------------------------------------------------------------------
__global__ __launch_bounds__(256) void k_gather(const ushort_t* __restrict__ msg,
                                                const int* __restrict__ idx,
                                                ushort_t* __restrict__ nei) {
    const int task = blockIdx.x * 256 + threadIdx.x;
    const int row  = task >> 4;
    const int c0   = (task & 15) * 8;
    const int* ip = idx + (size_t)row * MAX_NB;
    const int j0 = ip[0], j1 = ip[1], j2 = ip[2], j3 = ip[3], j4 = ip[4], j5 = ip[5];
    const uint4 v0 = *(const uint4*)(msg + (size_t)j0 * H + c0);
    const uint4 v1 = *(const uint4*)(msg + (size_t)j1 * H + c0);
    const uint4 v2 = *(const uint4*)(msg + (size_t)j2 * H + c0);
    const uint4 v3 = *(const uint4*)(msg + (size_t)j3 * H + c0);
    const uint4 v4 = *(const uint4*)(msg + (size_t)j4 * H + c0);
    const uint4 v5 = *(const uint4*)(msg + (size_t)j5 * H + c0);
    float a[8];
#pragma unroll
    for (int q = 0; q < 8; ++q) a[q] = 0.f;
    addv(a, v0); addv(a, v1); addv(a, v2); addv(a, v3); addv(a, v4); addv(a, v5);
    uint4 u;
    u.x = pack2(a[0], a[1]); u.y = pack2(a[2], a[3]);
    u.z = pack2(a[4], a[5]); u.w = pack2(a[6], a[7]);
    *(uint4*)(nei + (size_t)row * H + c0) = u;
}

// ---------------------------------------------------------------------------
// Gather (atoms): builds A matrix [N_ATOMS][192] bf16:
//   cols 0..127 = sum_j msg[agraph[row][j]], cols 128..166 = fatoms, rest 0.
// 24 col-groups per row; exact grid (100000*24/256 = 9375).
// ---------------------------------------------------------------------------
__global__ __launch_bounds__(256) void k_gather_a(const ushort_t* __restrict__ msg,
                                                  const int* __restrict__ agraph,
                                                  const float* __restrict__ fatoms,
                                                  ushort_t* __restrict__ a_in) {
    const int task = blockIdx.x * 256 + threadIdx.x;
    const int row  = task / 24;
    const int cg   = task % 24;
    if (cg < 16) {
        const int c0 = cg * 8;
        const int* ip = agraph + (size_t)row * MAX_NB;
        const int j0 = ip[0], j1 = ip[1], j2 = ip[2], j3 = ip[3], j4 = ip[4], j5 = ip[5];
        const uint4 v0 = *(const uint4*)(msg + (size_t)j0 * H + c0);
        const uint4 v1 = *(const uint4*)(msg + (size_t)j1 * H + c0);
        const uint4 v2 = *(const uint4*)(msg + (size_t)j2 * H + c0);
        const uint4 v3 = *(const uint4*)(msg + (size_t)j3 * H + c0);
        const uint4 v4 = *(const uint4*)(msg + (size_t)j4 * H + c0);
        const uint4 v5 = *(const uint4*)(msg + (size_t)j5 * H + c0);
        float a[8];
#pragma unroll
        for (int q = 0; q < 8; ++q) a[q] = 0.f;
        addv(a, v0); addv(a, v1); addv(a, v2); addv(a, v3); addv(a, v4); addv(a, v5);
        uint4 u;
        u.x = pack2(a[0], a[1]); u.y = pack2(a[2], a[3]);
        u.z = pack2(a[4], a[5]); u.w = pack2(a[6], a[7]);
        *(uint4*)(a_in + (size_t)row * KO + c0) = u;
    } else {
        const int c = (cg - 16) * 8;           // feature base within 64-wide tail
        float a[8];
#pragma unroll
        for (int q = 0; q < 8; ++q) {
            const int f = c + q;
            a[q] = (f < AF) ? fatoms[(size_t)row * AF + f] : 0.f;
        }
        uint4 u;
        u.x = pack2(a[0], a[1]); u.y = pack2(a[2], a[3]);
        u.z = pack2(a[4], a[5]); u.w = pack2(a[6], a[7]);
        *(uint4*)(a_in + (size_t)row * KO + H + c) = u;
    }
}

// ---------------------------------------------------------------------------
// MP GEMM (dense, in-place): msg[b] = relu(binput[b] + nei[b] @ W_h^T)
// nei == msg buffer (each block touches only its own 64 rows).
// A-frags direct from global; W_h staged bf16 in LDS; C staged via LDS union.
// LDS = max(sB 34816, sC 33792) = 34816 B -> 4 blocks/CU.
// ---------------------------------------------------------------------------
__global__ __launch_bounds__(256) void k_mp_gemm(const float* __restrict__ W_h,
                                                 const ushort_t* __restrict__ binput,
                                                 ushort_t* __restrict__ msg) {
    __shared__ __align__(16) unsigned char smem[H * 136 * 2];   // 34816
    ushort_t (*sB)[136] = (ushort_t(*)[136])smem;
    float    (*sC)[132] = (float(*)[132])smem;

    const int t  = threadIdx.x;
    const int b0 = blockIdx.x * 64;
    const int w    = t >> 6;
    const int lane = t & 63;
    const int col  = lane & 15;
    const int kg   = lane >> 4;
    const int m    = 16 * w + col;

    // prefetch A-fragments (this block's own rows of the gathered nei)
    bf16x8 af[4];
    const ushort_t* arow = msg + (size_t)(b0 + m) * H;
#pragma unroll
    for (int ks = 0; ks < 4; ++ks)
        af[ks] = *(const bf16x8*)(arow + ks * 32 + kg * 8);

    // stage W_h -> bf16 LDS (float4 loads, b64 LDS writes)
    const float4* W4 = (const float4*)W_h;
    for (int i = t; i < (H * H) / 4; i += 256) {
        const float4 v = W4[i];
        const int n = i >> 5, k0 = (i & 31) * 4;
        uint2 u; u.x = pack2(v.x, v.y); u.y = pack2(v.z, v.w);
        *(uint2*)&sB[n][k0] = u;
    }
    __syncthreads();

    f32x4 acc[8];
#pragma unroll
    for (int nt = 0; nt < 8; ++nt) acc[nt] = (f32x4){0.f, 0.f, 0.f, 0.f};
#pragma unroll
    for (int ks = 0; ks < 4; ++ks) {
        const int k = ks * 32 + kg * 8;
#pragma unroll
        for (int nt = 0; nt < 8; ++nt) {
            const bf16x8 b = *(const bf16x8*)&sB[nt * 16 + col][k];
            acc[nt] = __builtin_amdgcn_mfma_f32_16x16x32_bf16(af[ks], b, acc[nt], 0, 0, 0);
        }
    }
    __syncthreads();   // all waves done with sB (and A reads drained) -> reuse as sC

    const int row0 = kg * 4;
#pragma unroll
    for (int nt = 0; nt < 8; ++nt)
#pragma unroll
        for (int r = 0; r < 4; ++r)
            sC[16 * w + row0 + r][nt * 16 + col] = acc[nt][r];
    __syncthreads();

    for (int i = t; i < 64 * 16; i += 256) {
        const int row = i >> 4, c0 = (i & 15) * 8;
        const size_t off = (size_t)(b0 + row) * H + c0;
        const uint4 bi4 = *(const uint4*)(binput + off);
        const float* cp = &sC[row][c0];
        uint4 o; float v0, v1;
        v0 = bf2f((ushort_t)(bi4.x & 0xffffu)) + cp[0]; v1 = bf2f((ushort_t)(bi4.x >> 16)) + cp[1];
        o.x = pack2(v0 > 0.f ? v0 : 0.f, v1 > 0.f ? v1 : 0.f);
        v0 = bf2f((ushort_t)(bi4.y & 0xffffu)) + cp[2]; v1 = bf2f((ushort_t)(bi4.y >> 16)) + cp[3];
        o.y = pack2(v0 > 0.f ? v0 : 0.f, v1 > 0.f ? v1 : 0.f);
        v0 = bf2f((ushort_t)(bi4.z & 0xffffu)) + cp[4]; v1 = bf2f((ushort_t)(bi4.z >> 16)) + cp[5];
        o.z = pack2(v0 > 0.f ? v0 : 0.f, v1 > 0.f ? v1 : 0.f);
        v0 = bf2f((ushort_t)(bi4.w & 0xffffu)) + cp[6]; v1 = bf2f((ushort_t)(bi4.w >> 16)) + cp[7];
        o.w = pack2(v0 > 0.f ? v0 : 0.f, v1 > 0.f ? v1 : 0.f);
        *(uint4*)(msg + off) = o;
    }
}

// ---------------------------------------------------------------------------
// Output GEMM (dense): out = relu(b_o + a_in @ B^T), A [100000][192] bf16.
// B[n][k]: k<128 -> W_o[n][39+k]; 128<=k<167 -> W_o[n][k-128]; else 0.
// LDS = max(sB 51200, sC 33792) = 51200 B -> 3 blocks/CU.
// ---------------------------------------------------------------------------
__global__ __launch_bounds__(256) void k_out_gemm(const ushort_t* __restrict__ a_in,
                                                  const float* __restrict__ W_o,
                                                  const float* __restrict__ b_o,
                                                  float* __restrict__ out) {
    __shared__ __align__(16) unsigned char smem[H * 200 * 2];   // 51200
    ushort_t (*sB)[200] = (ushort_t(*)[200])smem;
    float    (*sC)[132] = (float(*)[132])smem;

    const int t  = threadIdx.x;
    const int a0 = blockIdx.x * 64;
    const int w    = t >> 6;
    const int lane = t & 63;
    const int col  = lane & 15;
    const int kg   = lane >> 4;
    const int m    = 16 * w + col;

    // prefetch A-fragments (OOB rows read workspace garbage; stores guarded)
    bf16x8 af[6];
    const ushort_t* arow = a_in + (size_t)(a0 + m) * KO;
#pragma unroll
    for (int ks = 0; ks < 6; ++ks)
        af[ks] = *(const bf16x8*)(arow + ks * 32 + kg * 8);

    for (int i = t; i < H * KO; i += 256) {
        const int n = i / KO, k = i % KO;
        float v = 0.f;
        if (k < H)            v = W_o[(size_t)n * (AF + H) + AF + k];
        else if (k < H + AF)  v = W_o[(size_t)n * (AF + H) + (k - H)];
        sB[n][k] = f2bf(v);
    }
    __syncthreads();

    f32x4 acc[8];
#pragma unroll
    for (int nt = 0; nt < 8; ++nt) acc[nt] = (f32x4){0.f, 0.f, 0.f, 0.f};
#pragma unroll
    for (int ks = 0; ks < 6; ++ks) {
        const int k = ks * 32 + kg * 8;
#pragma unroll
        for (int nt = 0; nt < 8; ++nt) {
            const bf16x8 b = *(const bf16x8*)&sB[nt * 16 + col][k];
            acc[nt] = __builtin_amdgcn_mfma_f32_16x16x32_bf16(af[ks], b, acc[nt], 0, 0, 0);
        }
    }
    __syncthreads();

    const int row0 = kg * 4;
#pragma unroll
    for (int nt = 0; nt < 8; ++nt)
#pragma unroll
        for (int r = 0; r < 4; ++r)
            sC[16 * w + row0 + r][nt * 16 + col] = acc[nt][r];
    __syncthreads();

    const float4* bo4 = (const float4*)b_o;
    for (int i = t; i < 64 * 16; i += 256) {
        const int row = i >> 4, c0 = (i & 15) * 8;
        const int a = a0 + row;
        if (a < N_ATOMS) {
            const float* cp = &sC[row][c0];
            const float4 b1 = bo4[c0 >> 2];
            const float4 b2 = bo4[(c0 >> 2) + 1];
            float4 o1, o2;
            o1.x = cp[0] + b1.x; o1.y = cp[1] + b1.y; o1.z = cp[2] + b1.z; o1.w = cp[3] + b1.w;
            o2.x = cp[4] + b2.x; o2.y = cp[5] + b2.y; o2.z = cp[6] + b2.z; o2.w = cp[7] + b2.w;
            o1.x = o1.x > 0.f ? o1.x : 0.f; o1.y = o1.y > 0.f ? o1.y : 0.f;
            o1.z = o1.z > 0.f ? o1.z : 0.f; o1.w = o1.w > 0.f ? o1.w : 0.f;
            o2.x = o2.x > 0.f ? o2.x : 0.f; o2.y = o2.y > 0.f ? o2.y : 0.f;
            o2.z = o2.z > 0.f ? o2.z : 0.f; o2.w = o2.w > 0.f ? o2.w : 0.f;
            float* op = out + (size_t)a * H + c0;
            *(float4*)op = o1;
            *(float4*)(op + 4) = o2;
        }
    }
}

// ---------------------------------------------------------------------------
extern "C" void kernel_launch(void* const* d_in, const int* in_sizes, int n_in,
                              void* d_out, int out_size, void* d_ws, size_t ws_size,
                              hipStream_t stream) {
    const float* fatoms = (const float*)d_in[0];
    const float* fbonds = (const float*)d_in[1];
    const int*   agraph = (const int*)d_in[2];
    const int*   bgraph = (const int*)d_in[3];
    const float* W_i    = (const float*)d_in[4];
    const float* W_h    = (const float*)d_in[5];
    const float* W_o    = (const float*)d_in[6];
    const float* b_o    = (const float*)d_in[7];
    float* out = (float*)d_out;

    const size_t MSG_BYTES = (size_t)N_BONDS * H * sizeof(ushort_t);   // 51.2 MB
    char* ws = (char*)d_ws;
    ushort_t* binput = (ushort_t*)(ws);
    ushort_t* msgA   = (ushort_t*)(ws + MSG_BYTES);
    ushort_t* msgB   = (ushort_t*)(ws + 2 * MSG_BYTES);

    k_binput<<<N_BONDS / 64, 256, 0, stream>>>(fbonds, W_i, binput, msgA);

    ushort_t* cur = msgA;
    ushort_t* nxt = msgB;
    for (int d = 0; d < DEPTH - 1; ++d) {
        // gather cur -> nxt, then in-place GEMM on nxt
        k_gather<<<(N_BONDS * 16) / 256, 256, 0, stream>>>(cur, bgraph, nxt);
        k_mp_gemm<<<N_BONDS / 64, 256, 0, stream>>>(W_h, binput, nxt);
        ushort_t* tmp = cur; cur = nxt; nxt = tmp;
    }

    // atom A-matrix into the free buffer, then dense output GEMM
    ushort_t* a_in = nxt;
    k_gather_a<<<(N_ATOMS * 24) / 256, 256, 0, stream>>>(cur, agraph, fatoms, a_in);
    k_out_gemm<<<(N_ATOMS + 63) / 64, 256, 0, stream>>>(a_in, W_o, b_o, out);
}

// Round 5
// 557.913 us; speedup vs baseline: 2.4094x; 1.2784x over previous
//
#include <hip/hip_runtime.h>

#define N_ATOMS   100000
#define N_BONDS   200000
#define MAX_NB    6
#define AF        39
#define BFEAT     50      // 39 + 11
#define H         128
#define DEPTH     6
#define KO        192     // out GEMM K: 128 (a_nei) + 39 (fatoms) + 25 pad
#define KS_I      2       // k-steps (32 each) for the three GEMMs
#define KS_H      4
#define KS_O      6

typedef unsigned short ushort_t;
typedef unsigned int   uint_t;

typedef __attribute__((ext_vector_type(8))) short  bf16x8;
typedef __attribute__((ext_vector_type(4))) float  f32x4;

__device__ inline float bf2f(ushort_t u) {
    union { uint_t i; float f; } v; v.i = ((uint_t)u) << 16; return v.f;
}
__device__ inline ushort_t f2bf(float f) {
    union { float f; uint_t i; } v; v.f = f;
    uint_t x = v.i;
    uint_t r = (x + 0x7fffu + ((x >> 16) & 1u)) >> 16;   // RNE
    return (ushort_t)r;
}
__device__ inline uint_t pack2(float a, float b) {
    return (uint_t)f2bf(a) | ((uint_t)f2bf(b) << 16);
}
__device__ inline void addv(float* a, uint4 v) {
    a[0] += bf2f((ushort_t)(v.x & 0xffffu)); a[1] += bf2f((ushort_t)(v.x >> 16));
    a[2] += bf2f((ushort_t)(v.y & 0xffffu)); a[3] += bf2f((ushort_t)(v.y >> 16));
    a[4] += bf2f((ushort_t)(v.z & 0xffffu)); a[5] += bf2f((ushort_t)(v.z >> 16));
    a[6] += bf2f((ushort_t)(v.w & 0xffffu)); a[7] += bf2f((ushort_t)(v.w >> 16));
}

// ---------------------------------------------------------------------------
// Prep: pack W_i / W_h / W_o into MFMA B-fragment-major bf16 layout:
//   p[ks][nt][lane][j]  with  n = nt*16 + (lane&15),  k = ks*32 + (lane>>4)*8 + j
// so a wave's B-frag load for (ks,nt) is one coalesced 1 KB global read.
// Groups (16B each): Wi 1024, Wh 2048, Wo 3072 -> 6144 threads, 24 blocks.
// ---------------------------------------------------------------------------
__global__ __launch_bounds__(256) void k_pack(const float* __restrict__ W_i,
                                              const float* __restrict__ W_h,
                                              const float* __restrict__ W_o,
                                              ushort_t* __restrict__ pWi,
                                              ushort_t* __restrict__ pWh,
                                              ushort_t* __restrict__ pWo) {
    int id = blockIdx.x * 256 + threadIdx.x;
    int mat;
    ushort_t* dst;
    if (id < 1024)        { mat = 0; dst = pWi; }
    else if (id < 3072)   { mat = 1; dst = pWh; id -= 1024; }
    else                  { mat = 2; dst = pWo; id -= 3072; }
    const int lane = id & 63;
    const int nt   = (id >> 6) & 7;
    const int ks   = id >> 9;
    const int n  = nt * 16 + (lane & 15);
    const int k0 = ks * 32 + (lane >> 4) * 8;
    float v[8];
#pragma unroll
    for (int j = 0; j < 8; ++j) {
        const int k = k0 + j;
        float x = 0.f;
        if (mat == 0)      { if (k < BFEAT) x = W_i[n * BFEAT + k]; }
        else if (mat == 1) { x = W_h[n * H + k]; }
        else {
            if (k < H)          x = W_o[(size_t)n * (AF + H) + AF + k];
            else if (k < H + AF) x = W_o[(size_t)n * (AF + H) + (k - H)];
        }
        v[j] = x;
    }
    uint4 u;
    u.x = pack2(v[0], v[1]); u.y = pack2(v[2], v[3]);
    u.z = pack2(v[4], v[5]); u.w = pack2(v[6], v[7]);
    ((uint4*)dst)[id] = u;
}

// ---------------------------------------------------------------------------
// Kernel 1: binput = fbonds @ W_i^T (bf16); msg = relu(binput) (bf16)
// B-frags from packed global; LDS = sA[64][72] bf16 U sC[64][132] f32 = 33.8KB
// ---------------------------------------------------------------------------
__global__ __launch_bounds__(256) void k_binput(const float* __restrict__ fbonds,
                                                const ushort_t* __restrict__ pWi,
                                                ushort_t* __restrict__ binput,
                                                ushort_t* __restrict__ msg) {
    __shared__ __align__(16) unsigned char smem[64 * 132 * 4];
    ushort_t (*sA)[72]  = (ushort_t(*)[72])smem;
    float    (*sC)[132] = (float(*)[132])smem;
    const int t = threadIdx.x;
    const int b0 = blockIdx.x * 64;

    for (int i = t; i < 64 * 64; i += 256) {
        const int row = i >> 6, k = i & 63;
        sA[row][k] = (k < BFEAT) ? f2bf(fbonds[(size_t)(b0 + row) * BFEAT + k]) : (ushort_t)0;
    }
    __syncthreads();

    const int w    = t >> 6;
    const int lane = t & 63;
    const int col  = lane & 15;
    const int kg   = lane >> 4;
    const int m    = 16 * w + col;

    f32x4 acc[8];
#pragma unroll
    for (int nt = 0; nt < 8; ++nt) acc[nt] = (f32x4){0.f, 0.f, 0.f, 0.f};
#pragma unroll
    for (int ks = 0; ks < KS_I; ++ks) {
        const bf16x8 a = *(const bf16x8*)&sA[m][ks * 32 + kg * 8];
#pragma unroll
        for (int nt = 0; nt < 8; ++nt) {
            const bf16x8 b = *(const bf16x8*)(pWi + (((size_t)(ks * 8 + nt) * 64 + lane) * 8));
            acc[nt] = __builtin_amdgcn_mfma_f32_16x16x32_bf16(a, b, acc[nt], 0, 0, 0);
        }
    }
    __syncthreads();

    const int row0 = kg * 4;
#pragma unroll
    for (int nt = 0; nt < 8; ++nt)
#pragma unroll
        for (int r = 0; r < 4; ++r)
            sC[16 * w + row0 + r][nt * 16 + col] = acc[nt][r];
    __syncthreads();

    for (int i = t; i < 64 * 16; i += 256) {
        const int row = i >> 4, c0 = (i & 15) * 8;
        const float* cp = &sC[row][c0];
        uint4 ob, om;
        float v0, v1, r0, r1;
        v0 = cp[0]; v1 = cp[1]; r0 = v0 > 0.f ? v0 : 0.f; r1 = v1 > 0.f ? v1 : 0.f;
        ob.x = pack2(v0, v1); om.x = pack2(r0, r1);
        v0 = cp[2]; v1 = cp[3]; r0 = v0 > 0.f ? v0 : 0.f; r1 = v1 > 0.f ? v1 : 0.f;
        ob.y = pack2(v0, v1); om.y = pack2(r0, r1);
        v0 = cp[4]; v1 = cp[5]; r0 = v0 > 0.f ? v0 : 0.f; r1 = v1 > 0.f ? v1 : 0.f;
        ob.z = pack2(v0, v1); om.z = pack2(r0, r1);
        v0 = cp[6]; v1 = cp[7]; r0 = v0 > 0.f ? v0 : 0.f; r1 = v1 > 0.f ? v1 : 0.f;
        ob.w = pack2(v0, v1); om.w = pack2(r0, r1);
        const size_t off = (size_t)(b0 + row) * H + c0;
        *(uint4*)(binput + off) = ob;
        *(uint4*)(msg + off)    = om;
    }
}

// ---------------------------------------------------------------------------
// Fused MP step: msg_out[b] = relu(binput[b] + (sum_j msg_in[bgraph[b][j]]) @ W_h^T)
// Gather into sA (bf16), MFMA with B-frags from packed global, C via sC union.
// LDS: union 33.8 KB + sIdx 1.5 KB -> 4 blocks/CU, 16 waves.
// ---------------------------------------------------------------------------
__global__ __launch_bounds__(256) void k_mp(const ushort_t* __restrict__ msg_in,
                                            const int* __restrict__ bgraph,
                                            const ushort_t* __restrict__ pWh,
                                            const ushort_t* __restrict__ binput,
                                            ushort_t* __restrict__ msg_out) {
    __shared__ __align__(16) unsigned char smem[64 * 132 * 4];   // 33792
    ushort_t (*sA)[136] = (ushort_t(*)[136])smem;
    float    (*sC)[132] = (float(*)[132])smem;
    __shared__ int sIdx[64][MAX_NB];
    const int t = threadIdx.x;
    const int b0 = blockIdx.x * 64;

    for (int i = t; i < 64 * MAX_NB; i += 256)
        sIdx[i / MAX_NB][i % MAX_NB] = bgraph[(size_t)b0 * MAX_NB + i];
    __syncthreads();

    {   // gather-sum -> bf16 A tile. 4 passes; thread = (row-in-pass, col-group)
        const int bi = t >> 4;
        const int c0 = (t & 15) * 8;
#pragma unroll
        for (int p = 0; p < 4; ++p) {
            const int i = p * 16 + bi;
            const int* ip = sIdx[i];
            const int j0 = ip[0], j1 = ip[1], j2 = ip[2], j3 = ip[3], j4 = ip[4], j5 = ip[5];
            const uint4 v0 = *(const uint4*)(msg_in + (size_t)j0 * H + c0);
            const uint4 v1 = *(const uint4*)(msg_in + (size_t)j1 * H + c0);
            const uint4 v2 = *(const uint4*)(msg_in + (size_t)j2 * H + c0);
            const uint4 v3 = *(const uint4*)(msg_in + (size_t)j3 * H + c0);
            const uint4 v4 = *(const uint4*)(msg_in + (size_t)j4 * H + c0);
            const uint4 v5 = *(const uint4*)(msg_in + (size_t)j5 * H + c0);
            float a[8];
#pragma unroll
            for (int q = 0; q < 8; ++q) a[q] = 0.f;
            addv(a, v0); addv(a, v1); addv(a, v2); addv(a, v3); addv(a, v4); addv(a, v5);
            uint4 u;
            u.x = pack2(a[0], a[1]); u.y = pack2(a[2], a[3]);
            u.z = pack2(a[4], a[5]); u.w = pack2(a[6], a[7]);
            *(uint4*)&sA[i][c0] = u;
        }
    }
    __syncthreads();

    const int w    = t >> 6;
    const int lane = t & 63;
    const int col  = lane & 15;
    const int kg   = lane >> 4;
    const int m    = 16 * w + col;

    f32x4 acc[8];
#pragma unroll
    for (int nt = 0; nt < 8; ++nt) acc[nt] = (f32x4){0.f, 0.f, 0.f, 0.f};
#pragma unroll
    for (int ks = 0; ks < KS_H; ++ks) {
        const bf16x8 a = *(const bf16x8*)&sA[m][ks * 32 + kg * 8];
#pragma unroll
        for (int nt = 0; nt < 8; ++nt) {
            const bf16x8 b = *(const bf16x8*)(pWh + (((size_t)(ks * 8 + nt) * 64 + lane) * 8));
            acc[nt] = __builtin_amdgcn_mfma_f32_16x16x32_bf16(a, b, acc[nt], 0, 0, 0);
        }
    }
    __syncthreads();

    const int row0 = kg * 4;
#pragma unroll
    for (int nt = 0; nt < 8; ++nt)
#pragma unroll
        for (int r = 0; r < 4; ++r)
            sC[16 * w + row0 + r][nt * 16 + col] = acc[nt][r];
    __syncthreads();

    for (int i = t; i < 64 * 16; i += 256) {
        const int row = i >> 4, c0 = (i & 15) * 8;
        const size_t off = (size_t)(b0 + row) * H + c0;
        const uint4 bi4 = *(const uint4*)(binput + off);
        const float* cp = &sC[row][c0];
        uint4 o; float v0, v1;
        v0 = bf2f((ushort_t)(bi4.x & 0xffffu)) + cp[0]; v1 = bf2f((ushort_t)(bi4.x >> 16)) + cp[1];
        o.x = pack2(v0 > 0.f ? v0 : 0.f, v1 > 0.f ? v1 : 0.f);
        v0 = bf2f((ushort_t)(bi4.y & 0xffffu)) + cp[2]; v1 = bf2f((ushort_t)(bi4.y >> 16)) + cp[3];
        o.y = pack2(v0 > 0.f ? v0 : 0.f, v1 > 0.f ? v1 : 0.f);
        v0 = bf2f((ushort_t)(bi4.z & 0xffffu)) + cp[4]; v1 = bf2f((ushort_t)(bi4.z >> 16)) + cp[5];
        o.z = pack2(v0 > 0.f ? v0 : 0.f, v1 > 0.f ? v1 : 0.f);
        v0 = bf2f((ushort_t)(bi4.w & 0xffffu)) + cp[6]; v1 = bf2f((ushort_t)(bi4.w >> 16)) + cp[7];
        o.w = pack2(v0 > 0.f ? v0 : 0.f, v1 > 0.f ? v1 : 0.f);
        *(uint4*)(msg_out + off) = o;
    }
}

// ---------------------------------------------------------------------------
// Fused output: out = relu(b_o + [a_nei | fatoms | 0] @ B^T)
// Gather a_nei + fatoms into sA[64][200] bf16; B-frags from packed global.
// LDS: union 33.8 KB + sIdx 1.5 KB -> 4 blocks/CU.
// ---------------------------------------------------------------------------
__global__ __launch_bounds__(256) void k_out(const ushort_t* __restrict__ msg,
                                             const int* __restrict__ agraph,
                                             const float* __restrict__ fatoms,
                                             const ushort_t* __restrict__ pWo,
                                             const float* __restrict__ b_o,
                                             float* __restrict__ out) {
    __shared__ __align__(16) unsigned char smem[64 * 132 * 4];   // 33792 (sA 25600)
    ushort_t (*sA)[200] = (ushort_t(*)[200])smem;
    float    (*sC)[132] = (float(*)[132])smem;
    __shared__ int sIdx[64][MAX_NB];
    const int t = threadIdx.x;
    const int a0 = blockIdx.x * 64;

    for (int i = t; i < 64 * MAX_NB; i += 256) {
        const int a = a0 + i / MAX_NB;
        sIdx[i / MAX_NB][i % MAX_NB] = (a < N_ATOMS) ? agraph[(size_t)a * MAX_NB + (i % MAX_NB)] : 0;
    }
    // cols 128..191: fatoms (39) then zero pad
    for (int i = t; i < 64 * 64; i += 256) {
        const int row = i >> 6, c = i & 63;
        const int a = a0 + row;
        float x = 0.f;
        if (c < AF && a < N_ATOMS) x = fatoms[(size_t)a * AF + c];
        sA[row][H + c] = f2bf(x);
    }
    __syncthreads();

    {   // a_nei gather -> cols 0..127
        const int bi = t >> 4;
        const int c0 = (t & 15) * 8;
#pragma unroll
        for (int p = 0; p < 4; ++p) {
            const int i = p * 16 + bi;
            const int* ip = sIdx[i];
            const int j0 = ip[0], j1 = ip[1], j2 = ip[2], j3 = ip[3], j4 = ip[4], j5 = ip[5];
            const uint4 v0 = *(const uint4*)(msg + (size_t)j0 * H + c0);
            const uint4 v1 = *(const uint4*)(msg + (size_t)j1 * H + c0);
            const uint4 v2 = *(const uint4*)(msg + (size_t)j2 * H + c0);
            const uint4 v3 = *(const uint4*)(msg + (size_t)j3 * H + c0);
            const uint4 v4 = *(const uint4*)(msg + (size_t)j4 * H + c0);
            const uint4 v5 = *(const uint4*)(msg + (size_t)j5 * H + c0);
            float a[8];
#pragma unroll
            for (int q = 0; q < 8; ++q) a[q] = 0.f;
            addv(a, v0); addv(a, v1); addv(a, v2); addv(a, v3); addv(a, v4); addv(a, v5);
            uint4 u;
            u.x = pack2(a[0], a[1]); u.y = pack2(a[2], a[3]);
            u.z = pack2(a[4], a[5]); u.w = pack2(a[6], a[7]);
            *(uint4*)&sA[i][c0] = u;
        }
    }
    __syncthreads();

    const int w    = t >> 6;
    const int lane = t & 63;
    const int col  = lane & 15;
    const int kg   = lane >> 4;
    const int m    = 16 * w + col;

    f32x4 acc[8];
#pragma unroll
    for (int nt = 0; nt < 8; ++nt) acc[nt] = (f32x4){0.f, 0.f, 0.f, 0.f};
#pragma unroll
    for (int ks = 0; ks < KS_O; ++ks) {
        const bf16x8 a = *(const bf16x8*)&sA[m][ks * 32 + kg * 8];
#pragma unroll
        for (int nt = 0; nt < 8; ++nt) {
            const bf16x8 b = *(const bf16x8*)(pWo + (((size_t)(ks * 8 + nt) * 64 + lane) * 8));
            acc[nt] = __builtin_amdgcn_mfma_f32_16x16x32_bf16(a, b, acc[nt], 0, 0, 0);
        }
    }
    __syncthreads();

    const int row0 = kg * 4;
#pragma unroll
    for (int nt = 0; nt < 8; ++nt)
#pragma unroll
        for (int r = 0; r < 4; ++r)
            sC[16 * w + row0 + r][nt * 16 + col] = acc[nt][r];
    __syncthreads();

    const float4* bo4 = (const float4*)b_o;
    for (int i = t; i < 64 * 16; i += 256) {
        const int row = i >> 4, c0 = (i & 15) * 8;
        const int a = a0 + row;
        if (a < N_ATOMS) {
            const float* cp = &sC[row][c0];
            const float4 b1 = bo4[c0 >> 2];
            const float4 b2 = bo4[(c0 >> 2) + 1];
            float4 o1, o2;
            o1.x = cp[0] + b1.x; o1.y = cp[1] + b1.y; o1.z = cp[2] + b1.z; o1.w = cp[3] + b1.w;
            o2.x = cp[4] + b2.x; o2.y = cp[5] + b2.y; o2.z = cp[6] + b2.z; o2.w = cp[7] + b2.w;
            o1.x = o1.x > 0.f ? o1.x : 0.f; o1.y = o1.y > 0.f ? o1.y : 0.f;
            o1.z = o1.z > 0.f ? o1.z : 0.f; o1.w = o1.w > 0.f ? o1.w : 0.f;
            o2.x = o2.x > 0.f ? o2.x : 0.f; o2.y = o2.y > 0.f ? o2.y : 0.f;
            o2.z = o2.z > 0.f ? o2.z : 0.f; o2.w = o2.w > 0.f ? o2.w : 0.f;
            float* op = out + (size_t)a * H + c0;
            *(float4*)op = o1;
            *(float4*)(op + 4) = o2;
        }
    }
}

// ---------------------------------------------------------------------------
extern "C" void kernel_launch(void* const* d_in, const int* in_sizes, int n_in,
                              void* d_out, int out_size, void* d_ws, size_t ws_size,
                              hipStream_t stream) {
    const float* fatoms = (const float*)d_in[0];
    const float* fbonds = (const float*)d_in[1];
    const int*   agraph = (const int*)d_in[2];
    const int*   bgraph = (const int*)d_in[3];
    const float* W_i    = (const float*)d_in[4];
    const float* W_h    = (const float*)d_in[5];
    const float* W_o    = (const float*)d_in[6];
    const float* b_o    = (const float*)d_in[7];
    float* out = (float*)d_out;

    const size_t MSG_BYTES = (size_t)N_BONDS * H * sizeof(ushort_t);   // 51.2 MB
    char* ws = (char*)d_ws;
    ushort_t* binput = (ushort_t*)(ws);
    ushort_t* msgA   = (ushort_t*)(ws + MSG_BYTES);
    ushort_t* msgB   = (ushort_t*)(ws + 2 * MSG_BYTES);
    ushort_t* pWi    = (ushort_t*)(ws + 3 * MSG_BYTES);                         // 16 KB
    ushort_t* pWh    = (ushort_t*)(ws + 3 * MSG_BYTES + 16 * 1024);             // 32 KB
    ushort_t* pWo    = (ushort_t*)(ws + 3 * MSG_BYTES + 48 * 1024);             // 48 KB

    k_pack<<<24, 256, 0, stream>>>(W_i, W_h, W_o, pWi, pWh, pWo);
    k_binput<<<N_BONDS / 64, 256, 0, stream>>>(fbonds, pWi, binput, msgA);

    ushort_t* cur = msgA;
    ushort_t* nxt = msgB;
    for (int d = 0; d < DEPTH - 1; ++d) {
        k_mp<<<N_BONDS / 64, 256, 0, stream>>>(cur, bgraph, pWh, binput, nxt);
        ushort_t* tmp = cur; cur = nxt; nxt = tmp;
    }

    k_out<<<(N_ATOMS + 63) / 64, 256, 0, stream>>>(cur, agraph, fatoms, pWo, b_o, out);
}

// Round 6
// 527.802 us; speedup vs baseline: 2.5468x; 1.0570x over previous
//
#include <hip/hip_runtime.h>

#define N_ATOMS   100000
#define N_BONDS   200000
#define MAX_NB    6
#define AF        39
#define BFEAT     50      // 39 + 11
#define H         128
#define DEPTH     6
#define KO        192     // out GEMM K: 128 (a_nei) + 39 (fatoms) + 25 pad
#define KS_I      2       // k-steps (32 each) for the three GEMMs
#define KS_H      4
#define KS_O      6

typedef unsigned short ushort_t;
typedef unsigned int   uint_t;

typedef __attribute__((ext_vector_type(8))) short  bf16x8;
typedef __attribute__((ext_vector_type(4))) float  f32x4;

__device__ inline float bf2f(ushort_t u) {
    union { uint_t i; float f; } v; v.i = ((uint_t)u) << 16; return v.f;
}
__device__ inline ushort_t f2bf(float f) {
    union { float f; uint_t i; } v; v.f = f;
    uint_t x = v.i;
    uint_t r = (x + 0x7fffu + ((x >> 16) & 1u)) >> 16;   // RNE
    return (ushort_t)r;
}
__device__ inline uint_t pack2(float a, float b) {
    return (uint_t)f2bf(a) | ((uint_t)f2bf(b) << 16);
}
__device__ inline uint_t relu2(uint_t w) {
    uint_t lo = w & 0xffffu, hi = w >> 16;
    if (lo & 0x8000u) lo = 0;
    if (hi & 0x8000u) hi = 0;
    return lo | (hi << 16);
}
__device__ inline void addv(float* a, uint4 v) {
    a[0] += bf2f((ushort_t)(v.x & 0xffffu)); a[1] += bf2f((ushort_t)(v.x >> 16));
    a[2] += bf2f((ushort_t)(v.y & 0xffffu)); a[3] += bf2f((ushort_t)(v.y >> 16));
    a[4] += bf2f((ushort_t)(v.z & 0xffffu)); a[5] += bf2f((ushort_t)(v.z >> 16));
    a[6] += bf2f((ushort_t)(v.w & 0xffffu)); a[7] += bf2f((ushort_t)(v.w >> 16));
}

// ---------------------------------------------------------------------------
// Prep: pack W_i / W_h / W_o into MFMA B-fragment-major bf16 layout:
//   p[ks][nt][lane][j]  with  n = nt*16 + (lane&15),  k = ks*32 + (lane>>4)*8 + j
// ---------------------------------------------------------------------------
__global__ __launch_bounds__(256) void k_pack(const float* __restrict__ W_i,
                                              const float* __restrict__ W_h,
                                              const float* __restrict__ W_o,
                                              ushort_t* __restrict__ pWi,
                                              ushort_t* __restrict__ pWh,
                                              ushort_t* __restrict__ pWo) {
    int id = blockIdx.x * 256 + threadIdx.x;
    int mat;
    ushort_t* dst;
    if (id < 1024)        { mat = 0; dst = pWi; }
    else if (id < 3072)   { mat = 1; dst = pWh; id -= 1024; }
    else                  { mat = 2; dst = pWo; id -= 3072; }
    const int lane = id & 63;
    const int nt   = (id >> 6) & 7;
    const int ks   = id >> 9;
    const int n  = nt * 16 + (lane & 15);
    const int k0 = ks * 32 + (lane >> 4) * 8;
    float v[8];
#pragma unroll
    for (int j = 0; j < 8; ++j) {
        const int k = k0 + j;
        float x = 0.f;
        if (mat == 0)      { if (k < BFEAT) x = W_i[n * BFEAT + k]; }
        else if (mat == 1) { x = W_h[n * H + k]; }
        else {
            if (k < H)          x = W_o[(size_t)n * (AF + H) + AF + k];
            else if (k < H + AF) x = W_o[(size_t)n * (AF + H) + (k - H)];
        }
        v[j] = x;
    }
    uint4 u;
    u.x = pack2(v[0], v[1]); u.y = pack2(v[2], v[3]);
    u.z = pack2(v[4], v[5]); u.w = pack2(v[6], v[7]);
    ((uint4*)dst)[id] = u;
}

// ---------------------------------------------------------------------------
// Kernel 1: binput = fbonds @ W_i^T (bf16); msg = relu(binput) (bf16)
// A and C share one bf16 LDS buffer [64][136] (17.4 KB) -> 8 blocks/CU.
// Each wave's C rows == its own A rows, so no barrier between MFMA and C-write.
// ---------------------------------------------------------------------------
__global__ __launch_bounds__(256) void k_binput(const float* __restrict__ fbonds,
                                                const ushort_t* __restrict__ pWi,
                                                ushort_t* __restrict__ binput,
                                                ushort_t* __restrict__ msg) {
    __shared__ __align__(16) ushort_t sAC[64][136];   // 17408 B
    const int t = threadIdx.x;
    const int b0 = blockIdx.x * 64;

    for (int i = t; i < 64 * 64; i += 256) {
        const int row = i >> 6, k = i & 63;
        sAC[row][k] = (k < BFEAT) ? f2bf(fbonds[(size_t)(b0 + row) * BFEAT + k]) : (ushort_t)0;
    }
    __syncthreads();

    const int w    = t >> 6;
    const int lane = t & 63;
    const int col  = lane & 15;
    const int kg   = lane >> 4;
    const int m    = 16 * w + col;

    f32x4 acc[8];
#pragma unroll
    for (int nt = 0; nt < 8; ++nt) acc[nt] = (f32x4){0.f, 0.f, 0.f, 0.f};
    bf16x8 af[KS_I];
#pragma unroll
    for (int ks = 0; ks < KS_I; ++ks)
        af[ks] = *(const bf16x8*)&sAC[m][ks * 32 + kg * 8];
#pragma unroll
    for (int ks = 0; ks < KS_I; ++ks) {
#pragma unroll
        for (int nt = 0; nt < 8; ++nt) {
            const bf16x8 b = *(const bf16x8*)(pWi + (((size_t)(ks * 8 + nt) * 64 + lane) * 8));
            acc[nt] = __builtin_amdgcn_mfma_f32_16x16x32_bf16(af[ks], b, acc[nt], 0, 0, 0);
        }
    }
    // C -> same LDS (own rows only; wave-lockstep makes this safe without barrier)
    const int row0 = kg * 4;
#pragma unroll
    for (int nt = 0; nt < 8; ++nt)
#pragma unroll
        for (int r = 0; r < 4; ++r)
            sAC[16 * w + row0 + r][nt * 16 + col] = f2bf(acc[nt][r]);
    __syncthreads();

    for (int i = t; i < 64 * 16; i += 256) {
        const int row = i >> 4, c0 = (i & 15) * 8;
        const uint4 v = *(const uint4*)&sAC[row][c0];
        uint4 rl;
        rl.x = relu2(v.x); rl.y = relu2(v.y); rl.z = relu2(v.z); rl.w = relu2(v.w);
        const size_t off = (size_t)(b0 + row) * H + c0;
        *(uint4*)(binput + off) = v;
        *(uint4*)(msg + off)    = rl;
    }
}

// ---------------------------------------------------------------------------
// Fused MP step: msg_out[b] = relu(binput[b] + (sum_j msg_in[bgraph[b][j]]) @ W_h^T)
// LDS: sAC union (17.4 KB) + sIdx (1.5 KB) -> ~19 KB -> 8 blocks/CU (32 waves).
// ---------------------------------------------------------------------------
__global__ __launch_bounds__(256) void k_mp(const ushort_t* __restrict__ msg_in,
                                            const int* __restrict__ bgraph,
                                            const ushort_t* __restrict__ pWh,
                                            const ushort_t* __restrict__ binput,
                                            ushort_t* __restrict__ msg_out) {
    __shared__ __align__(16) ushort_t sAC[64][136];   // 17408 B: gather-A, then bf16 C
    __shared__ int sIdx[64][MAX_NB];
    const int t = threadIdx.x;
    const int b0 = blockIdx.x * 64;

    for (int i = t; i < 64 * MAX_NB; i += 256)
        sIdx[i / MAX_NB][i % MAX_NB] = bgraph[(size_t)b0 * MAX_NB + i];
    __syncthreads();

    {   // gather-sum -> bf16 A tile. 4 passes; thread = (row-in-pass, col-group)
        const int bi = t >> 4;
        const int c0 = (t & 15) * 8;
#pragma unroll
        for (int p = 0; p < 4; ++p) {
            const int i = p * 16 + bi;
            const int* ip = sIdx[i];
            const int j0 = ip[0], j1 = ip[1], j2 = ip[2], j3 = ip[3], j4 = ip[4], j5 = ip[5];
            const uint4 v0 = *(const uint4*)(msg_in + (size_t)j0 * H + c0);
            const uint4 v1 = *(const uint4*)(msg_in + (size_t)j1 * H + c0);
            const uint4 v2 = *(const uint4*)(msg_in + (size_t)j2 * H + c0);
            const uint4 v3 = *(const uint4*)(msg_in + (size_t)j3 * H + c0);
            const uint4 v4 = *(const uint4*)(msg_in + (size_t)j4 * H + c0);
            const uint4 v5 = *(const uint4*)(msg_in + (size_t)j5 * H + c0);
            float a[8];
#pragma unroll
            for (int q = 0; q < 8; ++q) a[q] = 0.f;
            addv(a, v0); addv(a, v1); addv(a, v2); addv(a, v3); addv(a, v4); addv(a, v5);
            uint4 u;
            u.x = pack2(a[0], a[1]); u.y = pack2(a[2], a[3]);
            u.z = pack2(a[4], a[5]); u.w = pack2(a[6], a[7]);
            *(uint4*)&sAC[i][c0] = u;
        }
    }
    __syncthreads();

    const int w    = t >> 6;
    const int lane = t & 63;
    const int col  = lane & 15;
    const int kg   = lane >> 4;
    const int m    = 16 * w + col;

    f32x4 acc[8];
#pragma unroll
    for (int nt = 0; nt < 8; ++nt) acc[nt] = (f32x4){0.f, 0.f, 0.f, 0.f};
    bf16x8 af[KS_H];
#pragma unroll
    for (int ks = 0; ks < KS_H; ++ks)
        af[ks] = *(const bf16x8*)&sAC[m][ks * 32 + kg * 8];
#pragma unroll
    for (int ks = 0; ks < KS_H; ++ks) {
#pragma unroll
        for (int nt = 0; nt < 8; ++nt) {
            const bf16x8 b = *(const bf16x8*)(pWh + (((size_t)(ks * 8 + nt) * 64 + lane) * 8));
            acc[nt] = __builtin_amdgcn_mfma_f32_16x16x32_bf16(af[ks], b, acc[nt], 0, 0, 0);
        }
    }
    // bf16 C into own rows of sAC (no barrier needed: per-wave A region == C region)
    const int row0 = kg * 4;
#pragma unroll
    for (int nt = 0; nt < 8; ++nt)
#pragma unroll
        for (int r = 0; r < 4; ++r)
            sAC[16 * w + row0 + r][nt * 16 + col] = f2bf(acc[nt][r]);
    __syncthreads();

    for (int i = t; i < 64 * 16; i += 256) {
        const int row = i >> 4, c0 = (i & 15) * 8;
        const size_t off = (size_t)(b0 + row) * H + c0;
        const uint4 bi4 = *(const uint4*)(binput + off);
        const uint4 cc  = *(const uint4*)&sAC[row][c0];
        uint4 o; float v0, v1;
        v0 = bf2f((ushort_t)(bi4.x & 0xffffu)) + bf2f((ushort_t)(cc.x & 0xffffu));
        v1 = bf2f((ushort_t)(bi4.x >> 16))     + bf2f((ushort_t)(cc.x >> 16));
        o.x = pack2(v0 > 0.f ? v0 : 0.f, v1 > 0.f ? v1 : 0.f);
        v0 = bf2f((ushort_t)(bi4.y & 0xffffu)) + bf2f((ushort_t)(cc.y & 0xffffu));
        v1 = bf2f((ushort_t)(bi4.y >> 16))     + bf2f((ushort_t)(cc.y >> 16));
        o.y = pack2(v0 > 0.f ? v0 : 0.f, v1 > 0.f ? v1 : 0.f);
        v0 = bf2f((ushort_t)(bi4.z & 0xffffu)) + bf2f((ushort_t)(cc.z & 0xffffu));
        v1 = bf2f((ushort_t)(bi4.z >> 16))     + bf2f((ushort_t)(cc.z >> 16));
        o.z = pack2(v0 > 0.f ? v0 : 0.f, v1 > 0.f ? v1 : 0.f);
        v0 = bf2f((ushort_t)(bi4.w & 0xffffu)) + bf2f((ushort_t)(cc.w & 0xffffu));
        v1 = bf2f((ushort_t)(bi4.w >> 16))     + bf2f((ushort_t)(cc.w >> 16));
        o.w = pack2(v0 > 0.f ? v0 : 0.f, v1 > 0.f ? v1 : 0.f);
        *(uint4*)(msg_out + off) = o;
    }
}

// ---------------------------------------------------------------------------
// Fused output: out = relu(b_o + [a_nei | fatoms | 0] @ B^T)   (fp32 C staging)
// ---------------------------------------------------------------------------
__global__ __launch_bounds__(256) void k_out(const ushort_t* __restrict__ msg,
                                             const int* __restrict__ agraph,
                                             const float* __restrict__ fatoms,
                                             const ushort_t* __restrict__ pWo,
                                             const float* __restrict__ b_o,
                                             float* __restrict__ out) {
    __shared__ __align__(16) unsigned char smem[64 * 132 * 4];   // 33792 (sA 25600)
    ushort_t (*sA)[200] = (ushort_t(*)[200])smem;
    float    (*sC)[132] = (float(*)[132])smem;
    __shared__ int sIdx[64][MAX_NB];
    const int t = threadIdx.x;
    const int a0 = blockIdx.x * 64;

    for (int i = t; i < 64 * MAX_NB; i += 256) {
        const int a = a0 + i / MAX_NB;
        sIdx[i / MAX_NB][i % MAX_NB] = (a < N_ATOMS) ? agraph[(size_t)a * MAX_NB + (i % MAX_NB)] : 0;
    }
    for (int i = t; i < 64 * 64; i += 256) {
        const int row = i >> 6, c = i & 63;
        const int a = a0 + row;
        float x = 0.f;
        if (c < AF && a < N_ATOMS) x = fatoms[(size_t)a * AF + c];
        sA[row][H + c] = f2bf(x);
    }
    __syncthreads();

    {   // a_nei gather -> cols 0..127
        const int bi = t >> 4;
        const int c0 = (t & 15) * 8;
#pragma unroll
        for (int p = 0; p < 4; ++p) {
            const int i = p * 16 + bi;
            const int* ip = sIdx[i];
            const int j0 = ip[0], j1 = ip[1], j2 = ip[2], j3 = ip[3], j4 = ip[4], j5 = ip[5];
            const uint4 v0 = *(const uint4*)(msg + (size_t)j0 * H + c0);
            const uint4 v1 = *(const uint4*)(msg + (size_t)j1 * H + c0);
            const uint4 v2 = *(const uint4*)(msg + (size_t)j2 * H + c0);
            const uint4 v3 = *(const uint4*)(msg + (size_t)j3 * H + c0);
            const uint4 v4 = *(const uint4*)(msg + (size_t)j4 * H + c0);
            const uint4 v5 = *(const uint4*)(msg + (size_t)j5 * H + c0);
            float a[8];
#pragma unroll
            for (int q = 0; q < 8; ++q) a[q] = 0.f;
            addv(a, v0); addv(a, v1); addv(a, v2); addv(a, v3); addv(a, v4); addv(a, v5);
            uint4 u;
            u.x = pack2(a[0], a[1]); u.y = pack2(a[2], a[3]);
            u.z = pack2(a[4], a[5]); u.w = pack2(a[6], a[7]);
            *(uint4*)&sA[i][c0] = u;
        }
    }
    __syncthreads();

    const int w    = t >> 6;
    const int lane = t & 63;
    const int col  = lane & 15;
    const int kg   = lane >> 4;
    const int m    = 16 * w + col;

    f32x4 acc[8];
#pragma unroll
    for (int nt = 0; nt < 8; ++nt) acc[nt] = (f32x4){0.f, 0.f, 0.f, 0.f};
#pragma unroll
    for (int ks = 0; ks < KS_O; ++ks) {
        const bf16x8 a = *(const bf16x8*)&sA[m][ks * 32 + kg * 8];
#pragma unroll
        for (int nt = 0; nt < 8; ++nt) {
            const bf16x8 b = *(const bf16x8*)(pWo + (((size_t)(ks * 8 + nt) * 64 + lane) * 8));
            acc[nt] = __builtin_amdgcn_mfma_f32_16x16x32_bf16(a, b, acc[nt], 0, 0, 0);
        }
    }
    __syncthreads();

    const int row0 = kg * 4;
#pragma unroll
    for (int nt = 0; nt < 8; ++nt)
#pragma unroll
        for (int r = 0; r < 4; ++r)
            sC[16 * w + row0 + r][nt * 16 + col] = acc[nt][r];
    __syncthreads();

    const float4* bo4 = (const float4*)b_o;
    for (int i = t; i < 64 * 16; i += 256) {
        const int row = i >> 4, c0 = (i & 15) * 8;
        const int a = a0 + row;
        if (a < N_ATOMS) {
            const float* cp = &sC[row][c0];
            const float4 b1 = bo4[c0 >> 2];
            const float4 b2 = bo4[(c0 >> 2) + 1];
            float4 o1, o2;
            o1.x = cp[0] + b1.x; o1.y = cp[1] + b1.y; o1.z = cp[2] + b1.z; o1.w = cp[3] + b1.w;
            o2.x = cp[4] + b2.x; o2.y = cp[5] + b2.y; o2.z = cp[6] + b2.z; o2.w = cp[7] + b2.w;
            o1.x = o1.x > 0.f ? o1.x : 0.f; o1.y = o1.y > 0.f ? o1.y : 0.f;
            o1.z = o1.z > 0.f ? o1.z : 0.f; o1.w = o1.w > 0.f ? o1.w : 0.f;
            o2.x = o2.x > 0.f ? o2.x : 0.f; o2.y = o2.y > 0.f ? o2.y : 0.f;
            o2.z = o2.z > 0.f ? o2.z : 0.f; o2.w = o2.w > 0.f ? o2.w : 0.f;
            float* op = out + (size_t)a * H + c0;
            *(float4*)op = o1;
            *(float4*)(op + 4) = o2;
        }
    }
}

// ---------------------------------------------------------------------------
extern "C" void kernel_launch(void* const* d_in, const int* in_sizes, int n_in,
                              void* d_out, int out_size, void* d_ws, size_t ws_size,
                              hipStream_t stream) {
    const float* fatoms = (const float*)d_in[0];
    const float* fbonds = (const float*)d_in[1];
    const int*   agraph = (const int*)d_in[2];
    const int*   bgraph = (const int*)d_in[3];
    const float* W_i    = (const float*)d_in[4];
    const float* W_h    = (const float*)d_in[5];
    const float* W_o    = (const float*)d_in[6];
    const float* b_o    = (const float*)d_in[7];
    float* out = (float*)d_out;

    const size_t MSG_BYTES = (size_t)N_BONDS * H * sizeof(ushort_t);   // 51.2 MB
    char* ws = (char*)d_ws;
    ushort_t* binput = (ushort_t*)(ws);
    ushort_t* msgA   = (ushort_t*)(ws + MSG_BYTES);
    ushort_t* msgB   = (ushort_t*)(ws + 2 * MSG_BYTES);
    ushort_t* pWi    = (ushort_t*)(ws + 3 * MSG_BYTES);                         // 16 KB
    ushort_t* pWh    = (ushort_t*)(ws + 3 * MSG_BYTES + 16 * 1024);             // 32 KB
    ushort_t* pWo    = (ushort_t*)(ws + 3 * MSG_BYTES + 48 * 1024);             // 48 KB

    k_pack<<<24, 256, 0, stream>>>(W_i, W_h, W_o, pWi, pWh, pWo);
    k_binput<<<N_BONDS / 64, 256, 0, stream>>>(fbonds, pWi, binput, msgA);

    ushort_t* cur = msgA;
    ushort_t* nxt = msgB;
    for (int d = 0; d < DEPTH - 1; ++d) {
        k_mp<<<N_BONDS / 64, 256, 0, stream>>>(cur, bgraph, pWh, binput, nxt);
        ushort_t* tmp = cur; cur = nxt; nxt = tmp;
    }

    k_out<<<(N_ATOMS + 63) / 64, 256, 0, stream>>>(cur, agraph, fatoms, pWo, b_o, out);
}